// Round 18
// baseline (192.788 us; speedup 1.0000x reference)
//
#include <hip/hip_runtime.h>
#include <math.h>

typedef __attribute__((ext_vector_type(4))) float f32x4;
typedef __attribute__((ext_vector_type(8))) short short8;

#define DEV __device__ __forceinline__

DEV short f2bf(float f){
  union { float f; unsigned u; } v; v.f = f;
  unsigned r = v.u + 0x7fffu + ((v.u >> 16) & 1u);
  return (short)(r >> 16);
}
DEV float bf2f(short s){
  union { unsigned u; float f; } v; v.u = ((unsigned)(unsigned short)s) << 16; return v.f;
}
DEV float exp2_hw(float x){ float r; asm("v_exp_f32 %0, %1" : "=v"(r) : "v"(x)); return r; }
DEV float rcp_hw(float x){ float r; asm("v_rcp_f32 %0, %1" : "=v"(r) : "v"(x)); return r; }
DEV unsigned cvtpk(float a, float b){
  unsigned r; asm("v_cvt_pk_bf16_f32 %0, %1, %2" : "=v"(r) : "v"(a), "v"(b)); return r;
}
DEV void gload_lds16(const short* src, short* lds){
  __builtin_amdgcn_global_load_lds(
      (const __attribute__((address_space(1))) void*)src,
      (__attribute__((address_space(3))) void*)lds, 16, 0, 0);
}
DEV float gelu_fast(float v){
  float u = v * (0.79788456f + 0.03567741f * v * v);
  float e = exp2_hw(u * 2.88539008f);          // e^{2u}
  float th = 1.0f - 2.0f * rcp_hw(e + 1.0f);   // tanh(u)
  return 0.5f * v * (1.0f + th);
}

// ---------------- prep: 4 weight transposes + LN1(+x copy) in ONE launch ----------------
__global__ __launch_bounds__(256) void prep_kernel(
    const float* __restrict__ Wqkv, short* __restrict__ wqkv_t,
    const float* __restrict__ Wo,   short* __restrict__ wo_t,
    const float* __restrict__ W1,   short* __restrict__ w1_t,
    const float* __restrict__ W2,   short* __restrict__ w2_t,
    const float* __restrict__ x, const float* __restrict__ ln1g,
    const float* __restrict__ ln1b, short* __restrict__ h,
    float* __restrict__ xcopy)
{
  int bid = blockIdx.x;
  if (bid < 3072) {
    const float* W; short* Wt; int K, N, nbx, local;
    if (bid < 768)       { W = Wqkv; Wt = wqkv_t; K = 512;  N = 1536; nbx = 48; local = bid; }
    else if (bid < 1024) { W = Wo;   Wt = wo_t;   K = 512;  N = 512;  nbx = 16; local = bid - 768; }
    else if (bid < 2048) { W = W1;   Wt = w1_t;   K = 512;  N = 2048; nbx = 64; local = bid - 1024; }
    else                 { W = W2;   Wt = w2_t;   K = 2048; N = 512;  nbx = 16; local = bid - 2048; }
    __shared__ float tile[32][33];
    int nb = (local % nbx) * 32, kb = (local / nbx) * 32;
    int tx = threadIdx.x & 31, ty = threadIdx.x >> 5;
    #pragma unroll
    for (int i = ty; i < 32; i += 8)
      tile[i][tx] = W[(size_t)(kb + i) * N + nb + tx];
    __syncthreads();
    #pragma unroll
    for (int i = ty; i < 32; i += 8)
      Wt[(size_t)(nb + i) * K + kb + tx] = f2bf(tile[tx][i]);
    return;
  }
  // ---- LN1 (one row per wave) + x pass-through copy ----
  int row  = (bid - 3072) * 4 + (threadIdx.x >> 6);
  int lane = threadIdx.x & 63;
  const float* xr = x + (size_t)row * 512 + lane * 8;
  f32x4 v0 = *(const f32x4*)(xr);
  f32x4 v1 = *(const f32x4*)(xr + 4);
  float s  = (v0[0]+v0[1]+v0[2]+v0[3]) + (v1[0]+v1[1]+v1[2]+v1[3]);
  float sq = (v0[0]*v0[0]+v0[1]*v0[1]+v0[2]*v0[2]+v0[3]*v0[3])
           + (v1[0]*v1[0]+v1[1]*v1[1]+v1[2]*v1[2]+v1[3]*v1[3]);
  #pragma unroll
  for (int off = 1; off < 64; off <<= 1) {
    s  += __shfl_xor(s, off);
    sq += __shfl_xor(sq, off);
  }
  float mu  = s * (1.0f / 512.0f);
  float var = sq * (1.0f / 512.0f) - mu * mu;
  float rstd = rsqrtf(var + 1e-5f);
  f32x4 g0 = *(const f32x4*)(ln1g + lane * 8);
  f32x4 g1 = *(const f32x4*)(ln1g + lane * 8 + 4);
  f32x4 b0 = *(const f32x4*)(ln1b + lane * 8);
  f32x4 b1 = *(const f32x4*)(ln1b + lane * 8 + 4);
  float o[8];
  #pragma unroll
  for (int j = 0; j < 4; ++j) o[j]     = (v0[j] - mu) * rstd * g0[j] + b0[j];
  #pragma unroll
  for (int j = 0; j < 4; ++j) o[4 + j] = (v1[j] - mu) * rstd * g1[j] + b1[j];
  uint4 pk;
  pk.x = cvtpk(o[0], o[1]); pk.y = cvtpk(o[2], o[3]);
  pk.z = cvtpk(o[4], o[5]); pk.w = cvtpk(o[6], o[7]);
  *(uint4*)(h + (size_t)row * 512 + lane * 8) = pk;
  float* xc = xcopy + (size_t)row * 512 + lane * 8;
  *(f32x4*)(xc)     = v0;
  *(f32x4*)(xc + 4) = v1;
}

// ---------------- layernorm, bf16 input (one row per wave) ----------------
__global__ __launch_bounds__(256) void ln_bf_kernel(
    const short* __restrict__ x, const float* __restrict__ g,
    const float* __restrict__ b, short* __restrict__ out)
{
  int row  = blockIdx.x * 4 + (threadIdx.x >> 6);
  int lane = threadIdx.x & 63;
  short8 raw = *(const short8*)(x + (size_t)row * 512 + lane * 8);
  float v[8];
  #pragma unroll
  for (int j = 0; j < 8; ++j) v[j] = bf2f(raw[j]);
  float s = 0.f, sq = 0.f;
  #pragma unroll
  for (int j = 0; j < 8; ++j) { s += v[j]; sq += v[j] * v[j]; }
  #pragma unroll
  for (int off = 1; off < 64; off <<= 1) {
    s  += __shfl_xor(s, off);
    sq += __shfl_xor(sq, off);
  }
  float mu  = s * (1.0f / 512.0f);
  float var = sq * (1.0f / 512.0f) - mu * mu;
  float rstd = rsqrtf(var + 1e-5f);
  f32x4 g0 = *(const f32x4*)(g + lane * 8);
  f32x4 g1 = *(const f32x4*)(g + lane * 8 + 4);
  f32x4 b0 = *(const f32x4*)(b + lane * 8);
  f32x4 b1 = *(const f32x4*)(b + lane * 8 + 4);
  float o[8];
  #pragma unroll
  for (int j = 0; j < 4; ++j) o[j]     = (v[j] - mu) * rstd * g0[j] + b0[j];
  #pragma unroll
  for (int j = 0; j < 4; ++j) o[4 + j] = (v[4+j] - mu) * rstd * g1[j] + b1[j];
  uint4 pk;
  pk.x = cvtpk(o[0], o[1]); pk.y = cvtpk(o[2], o[3]);
  pk.z = cvtpk(o[4], o[5]); pk.w = cvtpk(o[6], o[7]);
  *(uint4*)(out + (size_t)row * 512 + lane * 8) = pk;
}

// ---------------- small-tile GEMM (Wo / W2): BM=64, BN=128, BK=64 ----------------
// EPI: 4 +bias+resid(f32)->bf16 ; 5 +bias+resid(bf16)->f32
template<int EPI, int BM, typename OutT>
__global__ __launch_bounds__(256) void gemm_bt_kernel(
    const short* __restrict__ A, const short* __restrict__ Bt,
    OutT* __restrict__ C, const float* __restrict__ bias,
    const float* __restrict__ resid, const short* __restrict__ residb,
    int M, int N, int K)
{
  constexpr int MFR = BM / 32;
  constexpr int NFR = 4;
  constexpr int AI  = BM / 32;
  constexpr int BUF = (BM + 128) * 64;
  __shared__ __align__(16) short smem[3 * BUF];

  int tid = threadIdx.x;
  int lane = tid & 63, wid = tid >> 6;
  int l16 = lane & 15, lq = lane >> 4;

  int gx = gridDim.x;
  int nwg = gx * gridDim.y;
  int orig = blockIdx.y * gx + blockIdx.x;
  int swz = (orig & 7) * (nwg >> 3) + (orig >> 3);
  int bn = swz % gx, bm = swz / gx;

  int wm = wid >> 1, wn = wid & 1;

  const short* gaP[AI];
  const short* gbP[4];
  #pragma unroll
  for (int i = 0; i < AI; ++i) {
    int g = i * 4 + wid;
    gaP[i] = A + (size_t)(bm * BM + (g >> 1) * 16 + l16) * K + (g & 1) * 32 + lq * 8;
  }
  #pragma unroll
  for (int i = 0; i < 4; ++i) {
    int g = i * 4 + wid;
    gbP[i] = Bt + (size_t)(bn * 128 + (g >> 1) * 16 + l16) * K + (g & 1) * 32 + lq * 8;
  }

  auto STAGE = [&](int bufi, int k0) {
    short* base = smem + bufi * BUF;
    #pragma unroll
    for (int i = 0; i < AI; ++i)
      gload_lds16(gaP[i] + k0, base + (i * 4 + wid) * 512);
    #pragma unroll
    for (int i = 0; i < 4; ++i)
      gload_lds16(gbP[i] + k0, base + BM * 64 + (i * 4 + wid) * 512);
  };

  f32x4 acc[MFR][NFR] = {};

  STAGE(0, 0);
  STAGE(1, 64);

  int nt = K >> 6;
  for (int t = 0; t < nt; ++t) {
    if (t + 1 < nt) asm volatile("s_waitcnt vmcnt(6)" ::: "memory");
    else            asm volatile("s_waitcnt vmcnt(0)" ::: "memory");
    __builtin_amdgcn_s_barrier();
    __builtin_amdgcn_sched_barrier(0);
    if (t + 2 < nt) STAGE((t + 2) % 3, (t + 2) << 6);

    const short* base = smem + (t % 3) * BUF;
    #pragma unroll
    for (int kc = 0; kc < 2; ++kc) {
      short8 af[MFR], bfr[NFR];
      #pragma unroll
      for (int m = 0; m < MFR; ++m)
        af[m] = *(const short8*)(base + ((wm * MFR + m) * 2 + kc) * 512 + lane * 8);
      #pragma unroll
      for (int n = 0; n < NFR; ++n)
        bfr[n] = *(const short8*)(base + BM * 64 + ((wn * NFR + n) * 2 + kc) * 512 + lane * 8);
      __builtin_amdgcn_s_setprio(1);
      #pragma unroll
      for (int m = 0; m < MFR; ++m)
        #pragma unroll
        for (int n = 0; n < NFR; ++n)
          acc[m][n] = __builtin_amdgcn_mfma_f32_16x16x32_bf16(af[m], bfr[n], acc[m][n], 0, 0, 0);
      __builtin_amdgcn_s_setprio(0);
    }
  }

  float bv[NFR];
  #pragma unroll
  for (int n = 0; n < NFR; ++n)
    bv[n] = bias[bn * 128 + (wn * NFR + n) * 16 + l16];

  #pragma unroll
  for (int m = 0; m < MFR; ++m) {
    #pragma unroll
    for (int r = 0; r < 4; ++r) {
      int row = bm * BM + (wm * MFR + m) * 16 + lq * 4 + r;
      #pragma unroll
      for (int n = 0; n < NFR; ++n) {
        int col = bn * 128 + (wn * NFR + n) * 16 + l16;
        float v = acc[m][n][r] + bv[n];
        if (EPI == 4) v += resid[(size_t)row * N + col];
        if (EPI == 5) v += bf2f(residb[(size_t)row * N + col]);
        if constexpr (sizeof(OutT) == 2)
          ((short*)C)[(size_t)row * N + col] = f2bf(v);
        else
          ((float*)C)[(size_t)row * N + col] = v;
      }
    }
  }
}

// ---------------- 8-phase 256x256 GEMM core (W1 + QKV variants) ----------------
template<int QKV>
__global__ __launch_bounds__(512, 2) void gemm8p_kernel(
    const short* __restrict__ A, const short* __restrict__ Bt,
    short* __restrict__ C, const float* __restrict__ bias,
    short* __restrict__ vt, int M, int N, int K)
{
  __shared__ __align__(16) short smem[2 * 32768];

  int tid = threadIdx.x;
  int lane = tid & 63, wid = tid >> 6;
  int l16 = lane & 15, lq = lane >> 4;
  int wm = wid >> 2, wn = wid & 3;

  int gx = gridDim.x;
  int nwg = gx * gridDim.y;
  int orig = blockIdx.y * gx + blockIdx.x;
  int swz = (orig & 7) * (nwg >> 3) + (orig >> 3);
  int bn = swz % gx, bm = swz / gx;

  const short* gaP[4];
  const short* gbP[4];
  #pragma unroll
  for (int i = 0; i < 4; ++i) {
    int idx = i * 512 + tid;
    int g = idx >> 6, ln = idx & 63;
    gaP[i] = A  + (size_t)(bm * 256 + (g >> 1) * 16 + (ln & 15)) * K
                + (g & 1) * 32 + (ln >> 4) * 8;
    gbP[i] = Bt + (size_t)(bn * 256 + (g >> 1) * 16 + (ln & 15)) * K
                + (g & 1) * 32 + (ln >> 4) * 8;
  }

  auto STAGE_A = [&](int buf, int k0) {
    short* dst = smem + buf * 32768;
    #pragma unroll
    for (int i = 0; i < 4; ++i)
      gload_lds16(gaP[i] + k0, dst + ((size_t)(i * 512 + tid)) * 8);
  };
  auto STAGE_B_LO = [&](int buf, int k0) {
    short* dst = smem + buf * 32768 + 16384;
    #pragma unroll
    for (int i = 0; i < 2; ++i)
      gload_lds16(gbP[i] + k0, dst + ((size_t)(i * 512 + tid)) * 8);
  };
  auto STAGE_B_HI = [&](int buf, int k0) {
    short* dst = smem + buf * 32768 + 16384;
    #pragma unroll
    for (int i = 2; i < 4; ++i)
      gload_lds16(gbP[i] + k0, dst + ((size_t)(i * 512 + tid)) * 8);
  };

  f32x4 acc[8][4] = {};

  STAGE_A(0, 0);
  STAGE_B_LO(0, 0); STAGE_B_HI(0, 0);
  STAGE_B_LO(1, 64); STAGE_B_HI(1, 64);
  asm volatile("s_waitcnt vmcnt(4)" ::: "memory");
  __builtin_amdgcn_s_barrier();

  int nt = K >> 6;
  for (int t = 0; t < nt; ++t) {
    int cur = t & 1;
    const short* As_ = smem + cur * 32768;
    const short* Bs_ = As_ + 16384;
    short8 bf[4][2];

    #pragma unroll
    for (int p = 0; p < 4; ++p) {
      short8 af[2][2];
      #pragma unroll
      for (int mm = 0; mm < 2; ++mm)
        #pragma unroll
        for (int kc = 0; kc < 2; ++kc)
          af[mm][kc] = *(const short8*)(As_ + ((wm * 8 + 2 * p + mm) * 2 + kc) * 512 + lane * 8);
      if (p == 0) {
        #pragma unroll
        for (int n = 0; n < 4; ++n)
          #pragma unroll
          for (int kc = 0; kc < 2; ++kc)
            bf[n][kc] = *(const short8*)(Bs_ + ((wn * 4 + n) * 2 + kc) * 512 + lane * 8);
      }
      if (p == 0 && t + 1 < nt) STAGE_A(cur ^ 1, (t + 1) << 6);
      if (p == 1 && t + 2 < nt) STAGE_B_LO(cur, (t + 2) << 6);
      if (p == 2 && t + 2 < nt) STAGE_B_HI(cur, (t + 2) << 6);

      __builtin_amdgcn_s_barrier();
      asm volatile("s_waitcnt lgkmcnt(0)" ::: "memory");
      __builtin_amdgcn_sched_barrier(0);
      __builtin_amdgcn_s_setprio(1);
      #pragma unroll
      for (int mm = 0; mm < 2; ++mm)
        #pragma unroll
        for (int n = 0; n < 4; ++n)
          #pragma unroll
          for (int kc = 0; kc < 2; ++kc)
            acc[2 * p + mm][n] = __builtin_amdgcn_mfma_f32_16x16x32_bf16(
                af[mm][kc], bf[n][kc], acc[2 * p + mm][n], 0, 0, 0);
      __builtin_amdgcn_s_setprio(0);
      if (p < 3) {
        __builtin_amdgcn_s_barrier();
      } else {
        if (t + 2 < nt) asm volatile("s_waitcnt vmcnt(4)" ::: "memory");
        else            asm volatile("s_waitcnt vmcnt(0)" ::: "memory");
        __builtin_amdgcn_s_barrier();
      }
    }
  }

  if (QKV == 1 && bn >= 4) {
    __syncthreads();
    short* T = smem;
    #pragma unroll
    for (int m = 0; m < 8; ++m)
      #pragma unroll
      for (int n = 0; n < 4; ++n) {
        int c = (wn * 4 + n) * 16 + l16;
        #pragma unroll
        for (int r = 0; r < 4; ++r) {
          int rowl = wm * 128 + m * 16 + lq * 4 + r;
          T[c * 256 + (rowl ^ ((c & 7) << 4))] = f2bf(acc[m][n][r]);
        }
      }
    __syncthreads();
    int b2 = bm >> 3;
    int nnb = (bm & 7) * 256;
    int tn = tid & 31, cw = tid >> 5;
    #pragma unroll
    for (int c8 = 0; c8 < 16; ++c8) {
      int c = c8 * 16 + cw;
      short8 v = *(const short8*)(T + c * 256 + ((tn * 8) ^ ((c & 7) << 4)));
      if (tn & 1) {
        short8 w;
        #pragma unroll
        for (int j = 0; j < 8; ++j) w[j] = v[j ^ 4];
        v = w;
      }
      int c2 = bn * 256 + c - 1024;
      int bh = b2 * 8 + (c2 >> 6);
      int d  = c2 & 63;
      *(short8*)(vt + ((size_t)(bh * 64 + d)) * 2048 + nnb + tn * 8) = v;
    }
    return;
  }

  float bv[4];
  if (QKV == 0) {
    #pragma unroll
    for (int n = 0; n < 4; ++n)
      bv[n] = bias[bn * 256 + (wn * 4 + n) * 16 + l16];
  }
  #pragma unroll
  for (int m = 0; m < 8; ++m) {
    #pragma unroll
    for (int r = 0; r < 4; ++r) {
      int row = bm * 256 + wm * 128 + m * 16 + lq * 4 + r;
      #pragma unroll
      for (int n = 0; n < 4; ++n) {
        int col = bn * 256 + (wn * 4 + n) * 16 + l16;
        float v = acc[m][n][r];
        if (QKV == 0) v = gelu_fast(v + bv[n]);
        C[(size_t)row * N + col] = f2bf(v);
      }
    }
  }
}

// ---------------- fused flash attention, split-KV x2, T15 double-pipeline ----------------
// Ring-3 K/V LDS (48KB), prefetch depth 2. Per interval: QK^T(t+1) -> s_next issued
// BEFORE softmax(t)/PV(t) (register-independent) so the scheduler co-issues QK MFMAs
// under softmax VALU. accS double-buffered with STATIC names (sA/sB, 2x unroll).
#define ZQKT(TT, SS) do {                                                          \
  int kk0_ = kslice + (TT) * 64;                                                   \
  const short* kls_ = smem + ((TT) % 3) * 4096;                                    \
  _Pragma("unroll") for (int s_ = 0; s_ < 4; ++s_) {                               \
    short8 kf0_ = *(const short8*)(kls_ + (s_ * 2 + 0) * 512 + lane * 8);          \
    short8 kf1_ = *(const short8*)(kls_ + (s_ * 2 + 1) * 512 + lane * 8);          \
    _Pragma("unroll") for (int qf_ = 0; qf_ < 2; ++qf_) {                          \
      f32x4 z_ = {};                                                               \
      z_ = __builtin_amdgcn_mfma_f32_16x16x32_bf16(kf0_, qfrag[qf_][0], z_, 0,0,0);\
      z_ = __builtin_amdgcn_mfma_f32_16x16x32_bf16(kf1_, qfrag[qf_][1], z_, 0,0,0);\
      SS[qf_][s_] = z_;                                                            \
    }                                                                              \
  }                                                                                \
  if ((q0 & ~63) == kk0_) {                                                        \
    _Pragma("unroll") for (int qf_ = 0; qf_ < 2; ++qf_) {                          \
      int qg_ = q0 + qf_ * 16 + l16;                                               \
      _Pragma("unroll") for (int s_ = 0; s_ < 4; ++s_)                             \
        _Pragma("unroll") for (int r_ = 0; r_ < 4; ++r_)                           \
          if (kk0_ + s_ * 16 + lq * 4 + r_ == qg_) SS[qf_][s_][r_] = -30000.f;     \
    }                                                                              \
  }                                                                                \
} while (0)

#define SMPV(TT, SS) do {                                                          \
  const short* vls_ = smem + 12288 + ((TT) % 3) * 4096;                            \
  short8 pa_[2][2];                                                                \
  _Pragma("unroll") for (int qf_ = 0; qf_ < 2; ++qf_) {                            \
    float sum_ = 0.f;                                                              \
    unsigned W_[4][2];                                                             \
    _Pragma("unroll") for (int s_ = 0; s_ < 4; ++s_) {                             \
      float p0_ = exp2_hw(SS[qf_][s_][0]);                                         \
      float p1_ = exp2_hw(SS[qf_][s_][1]);                                         \
      float p2_ = exp2_hw(SS[qf_][s_][2]);                                         \
      float p3_ = exp2_hw(SS[qf_][s_][3]);                                         \
      sum_ += (p0_ + p1_) + (p2_ + p3_);                                           \
      W_[s_][0] = cvtpk(p0_, p1_);                                                 \
      W_[s_][1] = cvtpk(p2_, p3_);                                                 \
    }                                                                              \
    sum_ += __shfl_xor(sum_, 16);                                                  \
    sum_ += __shfl_xor(sum_, 32);                                                  \
    l[qf_] += sum_;                                                                \
    unsigned K0_[2], S0_[2], K2_[2], S2_[2], R0_[2], R2_[2];                       \
    _Pragma("unroll") for (int w_ = 0; w_ < 2; ++w_) {                             \
      K0_[w_] = hi ? W_[1][w_] : W_[0][w_];                                        \
      S0_[w_] = hi ? W_[0][w_] : W_[1][w_];                                        \
      K2_[w_] = hi ? W_[3][w_] : W_[2][w_];                                        \
      S2_[w_] = hi ? W_[2][w_] : W_[3][w_];                                        \
    }                                                                              \
    _Pragma("unroll") for (int w_ = 0; w_ < 2; ++w_) {                             \
      R0_[w_] = (unsigned)__shfl_xor((int)S0_[w_], 32);                            \
      R2_[w_] = (unsigned)__shfl_xor((int)S2_[w_], 32);                            \
    }                                                                              \
    bool sw_ = (hi != lq0);                                                        \
    unsigned FA_[2], FB_[2], sA_[2], sB_[2], GA_[2], GB_[2];                       \
    _Pragma("unroll") for (int w_ = 0; w_ < 2; ++w_) {                             \
      sA_[w_] = sw_ ? K0_[w_] : R0_[w_];  FA_[w_] = sw_ ? R0_[w_] : K0_[w_];       \
      sB_[w_] = sw_ ? K2_[w_] : R2_[w_];  FB_[w_] = sw_ ? R2_[w_] : K2_[w_];       \
    }                                                                              \
    _Pragma("unroll") for (int w_ = 0; w_ < 2; ++w_) {                             \
      GA_[w_] = (unsigned)__shfl_xor((int)sA_[w_], 16);                            \
      GB_[w_] = (unsigned)__shfl_xor((int)sB_[w_], 16);                            \
    }                                                                              \
    union { unsigned u[4]; short8 s8; } p0u_, p1u_;                                \
    p0u_.u[0] = FA_[0]; p0u_.u[1] = FA_[1]; p0u_.u[2] = GA_[0]; p0u_.u[3] = GA_[1];\
    p1u_.u[0] = FB_[0]; p1u_.u[1] = FB_[1]; p1u_.u[2] = GB_[0]; p1u_.u[3] = GB_[1];\
    pa_[qf_][0] = p0u_.s8;                                                         \
    pa_[qf_][1] = p1u_.s8;                                                         \
  }                                                                                \
  _Pragma("unroll") for (int d_ = 0; d_ < 4; ++d_) {                               \
    short8 vf0_ = *(const short8*)(vls_ + (d_ * 2 + 0) * 512 + lane * 8);          \
    short8 vf1_ = *(const short8*)(vls_ + (d_ * 2 + 1) * 512 + lane * 8);          \
    _Pragma("unroll") for (int qf_ = 0; qf_ < 2; ++qf_) {                          \
      accO[qf_][d_] = __builtin_amdgcn_mfma_f32_16x16x32_bf16(vf0_, pa_[qf_][0], accO[qf_][d_], 0,0,0); \
      accO[qf_][d_] = __builtin_amdgcn_mfma_f32_16x16x32_bf16(vf1_, pa_[qf_][1], accO[qf_][d_], 0,0,0); \
    }                                                                              \
  }                                                                                \
} while (0)

__global__ __launch_bounds__(512, 2) void attn_kernel(
    const short* __restrict__ qkv, const short* __restrict__ vt,
    const float* __restrict__ temp_ptr,
    short* __restrict__ Op0, short* __restrict__ Op1, float* __restrict__ Lbuf)
{
  __shared__ __align__(16) short smem[24576];  // K ring[3][4096] | V ring[3][4096]

  int tid = threadIdx.x;
  int lane = tid & 63, wid = tid >> 6;         // wid 0..7
  int l16 = lane & 15, lq = lane >> 4;
  int hi = lq >> 1, lq0 = lq & 1;

  int orig = blockIdx.y * 8 + blockIdx.x;      // nwg = 512
  int swz = (orig & 7) * 64 + (orig >> 3);
  int qb = swz & 7;
  int rr = swz >> 3;
  int bh = rr & 31, slice = rr >> 5;
  int b = bh >> 3, h = bh & 7;

  const short* qbase = qkv + (size_t)b * 2048 * 1536 + h * 64;
  const short* kbase = qbase + 512;
  const short* vbase = vt + (size_t)bh * 64 * 2048;
  int kslice = slice * 1024;

  float scale = __expf(temp_ptr[0]) * 1.44269504f;
  int q0 = qb * 256 + wid * 32;

  short8 qfrag[2][2];
  #pragma unroll
  for (int qf = 0; qf < 2; ++qf) {
    int qrow = q0 + qf * 16 + l16;
    #pragma unroll
    for (int c = 0; c < 2; ++c) {
      short8 raw = *(const short8*)(qbase + (size_t)qrow * 1536 + c * 32 + lq * 8);
      short8 sc;
      #pragma unroll
      for (int j = 0; j < 8; ++j) sc[j] = f2bf(bf2f(raw[j]) * scale);
      qfrag[qf][c] = sc;
    }
  }

  f32x4 accO[2][4] = {};
  float l[2] = {0.f, 0.f};
  f32x4 sA[2][4], sB[2][4];

  auto STAGE = [&](int bufi, int k0) {
    int sub = wid >> 1, cc = wid & 1;
    const short* srcK = kbase + (size_t)(k0 + sub * 16 + l16) * 1536 + cc * 32 + lq * 8;
    gload_lds16(srcK, smem + bufi * 4096 + wid * 512);
    const short* srcV = vbase + (size_t)(sub * 16 + l16) * 2048 + k0 + cc * 32 + lq * 8;
    gload_lds16(srcV, smem + 12288 + bufi * 4096 + wid * 512);
  };

  // prologue: tile0 ready; tiles 1,2 in flight (depth-2 ring)
  STAGE(0, kslice);
  __syncthreads();                 // drains tile0
  ZQKT(0, sA);
  STAGE(1, kslice + 64);
  __syncthreads();                 // drains tile1
  STAGE(2, kslice + 128);

  #pragma unroll 1
  for (int j2 = 0; j2 < 8; ++j2) {
    int j = j2 * 2;
    // ---- even interval: QK(j+1)->sB first (independent), then SM/PV(j) on sA
    ZQKT(j + 1, sB);
    SMPV(j, sA);
    __syncthreads();               // drains STAGE(j+2); frees buf j%3
    if (j + 3 < 16) STAGE(j % 3, kslice + (j + 3) * 64);
    // ---- odd interval: QK(j+2)->sA, then SM/PV(j+1) on sB
    if (j + 2 < 16) ZQKT(j + 2, sA);
    SMPV(j + 1, sB);
    __syncthreads();               // drains STAGE(j+3); frees buf (j+1)%3
    if (j + 4 < 16) STAGE((j + 1) % 3, kslice + (j + 4) * 64);
  }

  short* op = slice ? Op1 : Op0;
  #pragma unroll
  for (int qf = 0; qf < 2; ++qf) {
    int qg = q0 + qf * 16 + l16;
    if (lq == 0) Lbuf[(size_t)(slice * 32 + bh) * 2048 + qg] = l[qf];
    size_t rowoff = (size_t)(b * 2048 + qg) * 512 + h * 64;
    #pragma unroll
    for (int d = 0; d < 4; ++d) {
      unsigned w0 = cvtpk(accO[qf][d][0], accO[qf][d][1]);
      unsigned w1 = cvtpk(accO[qf][d][2], accO[qf][d][3]);
      uint2 pk; pk.x = w0; pk.y = w1;
      *(uint2*)(op + rowoff + d * 16 + lq * 4) = pk;
    }
  }
}

// ---------------- split-KV combine: out = (O0+O1)/(l0+l1) ----------------
__global__ __launch_bounds__(256) void attn_combine_kernel(
    const short* __restrict__ Op0, const short* __restrict__ Op1,
    const float* __restrict__ Lbuf, short* __restrict__ out)
{
  int idx = blockIdx.x * 256 + threadIdx.x;
  size_t e = (size_t)idx * 8;
  int row = (int)(e >> 9);
  int col = (int)(e & 511);
  int b = row >> 11, q = row & 2047;
  int bh = b * 8 + (col >> 6);
  float l0 = Lbuf[(size_t)bh * 2048 + q];
  float l1 = Lbuf[(size_t)(32 + bh) * 2048 + q];
  float inv = rcp_hw(l0 + l1);
  short8 a = *(const short8*)(Op0 + e);
  short8 c = *(const short8*)(Op1 + e);
  float o[8];
  #pragma unroll
  for (int j = 0; j < 8; ++j) o[j] = (bf2f(a[j]) + bf2f(c[j])) * inv;
  uint4 pk;
  pk.x = cvtpk(o[0], o[1]); pk.y = cvtpk(o[2], o[3]);
  pk.z = cvtpk(o[4], o[5]); pk.w = cvtpk(o[6], o[7]);
  *(uint4*)(out + e) = pk;
}

// ---------------- launcher ----------------
extern "C" void kernel_launch(void* const* d_in, const int* in_sizes, int n_in,
                              void* d_out, int out_size, void* d_ws, size_t ws_size,
                              hipStream_t stream)
{
  const float* x    = (const float*)d_in[0];
  const float* ln1g = (const float*)d_in[1];
  const float* ln1b = (const float*)d_in[2];
  const float* Wqkv = (const float*)d_in[3];
  const float* temp = (const float*)d_in[4];
  const float* Wo   = (const float*)d_in[5];
  const float* bo   = (const float*)d_in[6];
  const float* ln2g = (const float*)d_in[7];
  const float* ln2b = (const float*)d_in[8];
  const float* W1   = (const float*)d_in[9];
  const float* b1   = (const float*)d_in[10];
  const float* W2   = (const float*)d_in[11];
  const float* b2   = (const float*)d_in[12];
  float* out = (float*)d_out;

  char* ws = (char*)d_ws;
  short* wqkv_t = (short*)(ws);                    // [1536][512] bf16; dead after qkv GEMM
  float* lpart  = (float*)(ws);                    //   reuse: l partials [2][32][2048] f32
  short* wo_t   = (short*)(ws + 1572864);          // [512][512]
  short* w1_t   = (short*)(ws + 2097152);          // [2048][512]
  short* w2_t   = (short*)(ws + 4194304);          // [512][2048]
  short* h      = (short*)(ws + 6291456);          // [8192][512] bf16 (LN out; O-partial slice1)
  short* qkv    = (short*)(ws + 14680064);         // [8192][1536] bf16
  short* attn   = (short*)(ws + 39845888);         // [8192][512] bf16 (slice0 -> combined)
  short* ybf    = (short*)(ws + 48234496);         // [8192][512] bf16 (after attn; overlays vt)
  short* vt     = (short*)(ws + 48234496);         // [32][64][2048] bf16 (dead once ybf written)
  short* t      = (short*)(ws + 14680064);         // [8192][2048] bf16 (reuses qkv)
  // ws high-water: 65,011,712 bytes (unchanged)

  const int M = 8192;

  prep_kernel<<<3072 + 2048, 256, 0, stream>>>(
      Wqkv, wqkv_t, Wo, wo_t, W1, w1_t, W2, w2_t,
      x, ln1g, ln1b, h, out + (size_t)M * 512);

  gemm8p_kernel<1><<<dim3(1536 / 256, M / 256), 512, 0, stream>>>(
      h, wqkv_t, qkv, nullptr, vt, M, 1536, 512);

  attn_kernel<<<dim3(8, 64), 512, 0, stream>>>(qkv, vt, temp, attn, h, lpart);
  attn_combine_kernel<<<M * 512 / 8 / 256, 256, 0, stream>>>(attn, h, lpart, attn);

  gemm_bt_kernel<4, 64, short><<<dim3(512 / 128, M / 64), 256, 0, stream>>>(
      attn, wo_t, ybf, bo, x, nullptr, M, 512, 512);

  ln_bf_kernel<<<M / 4, 256, 0, stream>>>(ybf, ln2g, ln2b, h);

  gemm8p_kernel<0><<<dim3(2048 / 256, M / 256), 512, 0, stream>>>(
      h, w1_t, t, b1, nullptr, M, 2048, 512);

  gemm_bt_kernel<5, 64, float><<<dim3(512 / 128, M / 64), 256, 0, stream>>>(
      t, w2_t, out, b2, nullptr, ybf, M, 512, 2048);
}

// Round 19
// 186.208 us; speedup vs baseline: 1.0353x; 1.0353x over previous
//
#include <hip/hip_runtime.h>
#include <math.h>

typedef __attribute__((ext_vector_type(4))) float f32x4;
typedef __attribute__((ext_vector_type(8))) short short8;

#define DEV __device__ __forceinline__

DEV short f2bf(float f){
  union { float f; unsigned u; } v; v.f = f;
  unsigned r = v.u + 0x7fffu + ((v.u >> 16) & 1u);
  return (short)(r >> 16);
}
DEV float bf2f(short s){
  union { unsigned u; float f; } v; v.u = ((unsigned)(unsigned short)s) << 16; return v.f;
}
DEV float exp2_hw(float x){ float r; asm("v_exp_f32 %0, %1" : "=v"(r) : "v"(x)); return r; }
DEV float rcp_hw(float x){ float r; asm("v_rcp_f32 %0, %1" : "=v"(r) : "v"(x)); return r; }
DEV unsigned cvtpk(float a, float b){
  unsigned r; asm("v_cvt_pk_bf16_f32 %0, %1, %2" : "=v"(r) : "v"(a), "v"(b)); return r;
}
DEV void gload_lds16(const short* src, short* lds){
  __builtin_amdgcn_global_load_lds(
      (const __attribute__((address_space(1))) void*)src,
      (__attribute__((address_space(3))) void*)lds, 16, 0, 0);
}
DEV float gelu_fast(float v){
  float u = v * (0.79788456f + 0.03567741f * v * v);
  float e = exp2_hw(u * 2.88539008f);          // e^{2u}
  float th = 1.0f - 2.0f * rcp_hw(e + 1.0f);   // tanh(u)
  return 0.5f * v * (1.0f + th);
}

// ---------------- prep: 4 weight transposes + LN1(+x copy) in ONE launch ----------------
__global__ __launch_bounds__(256) void prep_kernel(
    const float* __restrict__ Wqkv, short* __restrict__ wqkv_t,
    const float* __restrict__ Wo,   short* __restrict__ wo_t,
    const float* __restrict__ W1,   short* __restrict__ w1_t,
    const float* __restrict__ W2,   short* __restrict__ w2_t,
    const float* __restrict__ x, const float* __restrict__ ln1g,
    const float* __restrict__ ln1b, short* __restrict__ h,
    float* __restrict__ xcopy)
{
  int bid = blockIdx.x;
  if (bid < 3072) {
    const float* W; short* Wt; int K, N, nbx, local;
    if (bid < 768)       { W = Wqkv; Wt = wqkv_t; K = 512;  N = 1536; nbx = 48; local = bid; }
    else if (bid < 1024) { W = Wo;   Wt = wo_t;   K = 512;  N = 512;  nbx = 16; local = bid - 768; }
    else if (bid < 2048) { W = W1;   Wt = w1_t;   K = 512;  N = 2048; nbx = 64; local = bid - 1024; }
    else                 { W = W2;   Wt = w2_t;   K = 2048; N = 512;  nbx = 16; local = bid - 2048; }
    __shared__ float tile[32][33];
    int nb = (local % nbx) * 32, kb = (local / nbx) * 32;
    int tx = threadIdx.x & 31, ty = threadIdx.x >> 5;
    #pragma unroll
    for (int i = ty; i < 32; i += 8)
      tile[i][tx] = W[(size_t)(kb + i) * N + nb + tx];
    __syncthreads();
    #pragma unroll
    for (int i = ty; i < 32; i += 8)
      Wt[(size_t)(nb + i) * K + kb + tx] = f2bf(tile[tx][i]);
    return;
  }
  // ---- LN1 (one row per wave) + x pass-through copy ----
  int row  = (bid - 3072) * 4 + (threadIdx.x >> 6);
  int lane = threadIdx.x & 63;
  const float* xr = x + (size_t)row * 512 + lane * 8;
  f32x4 v0 = *(const f32x4*)(xr);
  f32x4 v1 = *(const f32x4*)(xr + 4);
  float s  = (v0[0]+v0[1]+v0[2]+v0[3]) + (v1[0]+v1[1]+v1[2]+v1[3]);
  float sq = (v0[0]*v0[0]+v0[1]*v0[1]+v0[2]*v0[2]+v0[3]*v0[3])
           + (v1[0]*v1[0]+v1[1]*v1[1]+v1[2]*v1[2]+v1[3]*v1[3]);
  #pragma unroll
  for (int off = 1; off < 64; off <<= 1) {
    s  += __shfl_xor(s, off);
    sq += __shfl_xor(sq, off);
  }
  float mu  = s * (1.0f / 512.0f);
  float var = sq * (1.0f / 512.0f) - mu * mu;
  float rstd = rsqrtf(var + 1e-5f);
  f32x4 g0 = *(const f32x4*)(ln1g + lane * 8);
  f32x4 g1 = *(const f32x4*)(ln1g + lane * 8 + 4);
  f32x4 b0 = *(const f32x4*)(ln1b + lane * 8);
  f32x4 b1 = *(const f32x4*)(ln1b + lane * 8 + 4);
  float o[8];
  #pragma unroll
  for (int j = 0; j < 4; ++j) o[j]     = (v0[j] - mu) * rstd * g0[j] + b0[j];
  #pragma unroll
  for (int j = 0; j < 4; ++j) o[4 + j] = (v1[j] - mu) * rstd * g1[j] + b1[j];
  uint4 pk;
  pk.x = cvtpk(o[0], o[1]); pk.y = cvtpk(o[2], o[3]);
  pk.z = cvtpk(o[4], o[5]); pk.w = cvtpk(o[6], o[7]);
  *(uint4*)(h + (size_t)row * 512 + lane * 8) = pk;
  float* xc = xcopy + (size_t)row * 512 + lane * 8;
  *(f32x4*)(xc)     = v0;
  *(f32x4*)(xc + 4) = v1;
}

// ---------------- layernorm, bf16 input (one row per wave) ----------------
__global__ __launch_bounds__(256) void ln_bf_kernel(
    const short* __restrict__ x, const float* __restrict__ g,
    const float* __restrict__ b, short* __restrict__ out)
{
  int row  = blockIdx.x * 4 + (threadIdx.x >> 6);
  int lane = threadIdx.x & 63;
  short8 raw = *(const short8*)(x + (size_t)row * 512 + lane * 8);
  float v[8];
  #pragma unroll
  for (int j = 0; j < 8; ++j) v[j] = bf2f(raw[j]);
  float s = 0.f, sq = 0.f;
  #pragma unroll
  for (int j = 0; j < 8; ++j) { s += v[j]; sq += v[j] * v[j]; }
  #pragma unroll
  for (int off = 1; off < 64; off <<= 1) {
    s  += __shfl_xor(s, off);
    sq += __shfl_xor(sq, off);
  }
  float mu  = s * (1.0f / 512.0f);
  float var = sq * (1.0f / 512.0f) - mu * mu;
  float rstd = rsqrtf(var + 1e-5f);
  f32x4 g0 = *(const f32x4*)(g + lane * 8);
  f32x4 g1 = *(const f32x4*)(g + lane * 8 + 4);
  f32x4 b0 = *(const f32x4*)(b + lane * 8);
  f32x4 b1 = *(const f32x4*)(b + lane * 8 + 4);
  float o[8];
  #pragma unroll
  for (int j = 0; j < 4; ++j) o[j]     = (v[j] - mu) * rstd * g0[j] + b0[j];
  #pragma unroll
  for (int j = 0; j < 4; ++j) o[4 + j] = (v[4+j] - mu) * rstd * g1[j] + b1[j];
  uint4 pk;
  pk.x = cvtpk(o[0], o[1]); pk.y = cvtpk(o[2], o[3]);
  pk.z = cvtpk(o[4], o[5]); pk.w = cvtpk(o[6], o[7]);
  *(uint4*)(out + (size_t)row * 512 + lane * 8) = pk;
}

// ---------------- small-tile GEMM (Wo / W2): BM=64, BN=128, BK=64 ----------------
// ring-3, prefetch depth 2, counted vmcnt(6). Fragment-major LDS.
// EPI: 4 +bias+resid(f32)->bf16 ; 5 +bias+resid(bf16)->f32
template<int EPI, int BM, typename OutT>
__global__ __launch_bounds__(256) void gemm_bt_kernel(
    const short* __restrict__ A, const short* __restrict__ Bt,
    OutT* __restrict__ C, const float* __restrict__ bias,
    const float* __restrict__ resid, const short* __restrict__ residb,
    int M, int N, int K)
{
  constexpr int MFR = BM / 32;
  constexpr int NFR = 4;
  constexpr int AI  = BM / 32;
  constexpr int BUF = (BM + 128) * 64;
  __shared__ __align__(16) short smem[3 * BUF];

  int tid = threadIdx.x;
  int lane = tid & 63, wid = tid >> 6;
  int l16 = lane & 15, lq = lane >> 4;

  int gx = gridDim.x;
  int nwg = gx * gridDim.y;
  int orig = blockIdx.y * gx + blockIdx.x;
  int swz = (orig & 7) * (nwg >> 3) + (orig >> 3);
  int bn = swz % gx, bm = swz / gx;

  int wm = wid >> 1, wn = wid & 1;

  const short* gaP[AI];
  const short* gbP[4];
  #pragma unroll
  for (int i = 0; i < AI; ++i) {
    int g = i * 4 + wid;
    gaP[i] = A + (size_t)(bm * BM + (g >> 1) * 16 + l16) * K + (g & 1) * 32 + lq * 8;
  }
  #pragma unroll
  for (int i = 0; i < 4; ++i) {
    int g = i * 4 + wid;
    gbP[i] = Bt + (size_t)(bn * 128 + (g >> 1) * 16 + l16) * K + (g & 1) * 32 + lq * 8;
  }

  auto STAGE = [&](int bufi, int k0) {
    short* base = smem + bufi * BUF;
    #pragma unroll
    for (int i = 0; i < AI; ++i)
      gload_lds16(gaP[i] + k0, base + (i * 4 + wid) * 512);
    #pragma unroll
    for (int i = 0; i < 4; ++i)
      gload_lds16(gbP[i] + k0, base + BM * 64 + (i * 4 + wid) * 512);
  };

  f32x4 acc[MFR][NFR] = {};

  STAGE(0, 0);
  STAGE(1, 64);

  int nt = K >> 6;
  for (int t = 0; t < nt; ++t) {
    if (t + 1 < nt) asm volatile("s_waitcnt vmcnt(6)" ::: "memory");
    else            asm volatile("s_waitcnt vmcnt(0)" ::: "memory");
    __builtin_amdgcn_s_barrier();
    __builtin_amdgcn_sched_barrier(0);
    if (t + 2 < nt) STAGE((t + 2) % 3, (t + 2) << 6);

    const short* base = smem + (t % 3) * BUF;
    #pragma unroll
    for (int kc = 0; kc < 2; ++kc) {
      short8 af[MFR], bfr[NFR];
      #pragma unroll
      for (int m = 0; m < MFR; ++m)
        af[m] = *(const short8*)(base + ((wm * MFR + m) * 2 + kc) * 512 + lane * 8);
      #pragma unroll
      for (int n = 0; n < NFR; ++n)
        bfr[n] = *(const short8*)(base + BM * 64 + ((wn * NFR + n) * 2 + kc) * 512 + lane * 8);
      __builtin_amdgcn_s_setprio(1);
      #pragma unroll
      for (int m = 0; m < MFR; ++m)
        #pragma unroll
        for (int n = 0; n < NFR; ++n)
          acc[m][n] = __builtin_amdgcn_mfma_f32_16x16x32_bf16(af[m], bfr[n], acc[m][n], 0, 0, 0);
      __builtin_amdgcn_s_setprio(0);
    }
  }

  float bv[NFR];
  #pragma unroll
  for (int n = 0; n < NFR; ++n)
    bv[n] = bias[bn * 128 + (wn * NFR + n) * 16 + l16];

  #pragma unroll
  for (int m = 0; m < MFR; ++m) {
    #pragma unroll
    for (int r = 0; r < 4; ++r) {
      int row = bm * BM + (wm * MFR + m) * 16 + lq * 4 + r;
      #pragma unroll
      for (int n = 0; n < NFR; ++n) {
        int col = bn * 128 + (wn * NFR + n) * 16 + l16;
        float v = acc[m][n][r] + bv[n];
        if (EPI == 4) v += resid[(size_t)row * N + col];
        if (EPI == 5) v += bf2f(residb[(size_t)row * N + col]);
        if constexpr (sizeof(OutT) == 2)
          ((short*)C)[(size_t)row * N + col] = f2bf(v);
        else
          ((float*)C)[(size_t)row * N + col] = v;
      }
    }
  }
}

// ---------------- 8-phase 256x256 GEMM core (W1 + QKV variants) ----------------
// wave-tile 128x64 (MFR=8), 2x64KB LDS dbuf, 4 phases per K-tile, counted vmcnt.
// QKV==0: +bias,GELU->bf16 (W1).  QKV==1: no bias; bn<4 plain bf16 C (N=1536);
//         bn>=4 whole tile is V -> vt via 256x256 LDS transpose (128KB reuse).
template<int QKV>
__global__ __launch_bounds__(512, 2) void gemm8p_kernel(
    const short* __restrict__ A, const short* __restrict__ Bt,
    short* __restrict__ C, const float* __restrict__ bias,
    short* __restrict__ vt, int M, int N, int K)
{
  __shared__ __align__(16) short smem[2 * 32768];   // 2 buf x (A 32KB + B 32KB)

  int tid = threadIdx.x;
  int lane = tid & 63, wid = tid >> 6;   // 8 waves
  int l16 = lane & 15, lq = lane >> 4;
  int wm = wid >> 2, wn = wid & 3;       // 2 waves (M) x 4 waves (N)

  int gx = gridDim.x;
  int nwg = gx * gridDim.y;
  int orig = blockIdx.y * gx + blockIdx.x;
  int swz = (orig & 7) * (nwg >> 3) + (orig >> 3);
  int bn = swz % gx, bm = swz / gx;

  const short* gaP[4];
  const short* gbP[4];
  #pragma unroll
  for (int i = 0; i < 4; ++i) {
    int idx = i * 512 + tid;
    int g = idx >> 6, ln = idx & 63;
    gaP[i] = A  + (size_t)(bm * 256 + (g >> 1) * 16 + (ln & 15)) * K
                + (g & 1) * 32 + (ln >> 4) * 8;
    gbP[i] = Bt + (size_t)(bn * 256 + (g >> 1) * 16 + (ln & 15)) * K
                + (g & 1) * 32 + (ln >> 4) * 8;
  }

  auto STAGE_A = [&](int buf, int k0) {
    short* dst = smem + buf * 32768;
    #pragma unroll
    for (int i = 0; i < 4; ++i)
      gload_lds16(gaP[i] + k0, dst + ((size_t)(i * 512 + tid)) * 8);
  };
  auto STAGE_B_LO = [&](int buf, int k0) {
    short* dst = smem + buf * 32768 + 16384;
    #pragma unroll
    for (int i = 0; i < 2; ++i)
      gload_lds16(gbP[i] + k0, dst + ((size_t)(i * 512 + tid)) * 8);
  };
  auto STAGE_B_HI = [&](int buf, int k0) {
    short* dst = smem + buf * 32768 + 16384;
    #pragma unroll
    for (int i = 2; i < 4; ++i)
      gload_lds16(gbP[i] + k0, dst + ((size_t)(i * 512 + tid)) * 8);
  };

  f32x4 acc[8][4] = {};

  STAGE_A(0, 0);
  STAGE_B_LO(0, 0); STAGE_B_HI(0, 0);
  STAGE_B_LO(1, 64); STAGE_B_HI(1, 64);
  asm volatile("s_waitcnt vmcnt(4)" ::: "memory");
  __builtin_amdgcn_s_barrier();

  int nt = K >> 6;
  for (int t = 0; t < nt; ++t) {
    int cur = t & 1;
    const short* As_ = smem + cur * 32768;
    const short* Bs_ = As_ + 16384;
    short8 bf[4][2];

    #pragma unroll
    for (int p = 0; p < 4; ++p) {
      short8 af[2][2];
      #pragma unroll
      for (int mm = 0; mm < 2; ++mm)
        #pragma unroll
        for (int kc = 0; kc < 2; ++kc)
          af[mm][kc] = *(const short8*)(As_ + ((wm * 8 + 2 * p + mm) * 2 + kc) * 512 + lane * 8);
      if (p == 0) {
        #pragma unroll
        for (int n = 0; n < 4; ++n)
          #pragma unroll
          for (int kc = 0; kc < 2; ++kc)
            bf[n][kc] = *(const short8*)(Bs_ + ((wn * 4 + n) * 2 + kc) * 512 + lane * 8);
      }
      if (p == 0 && t + 1 < nt) STAGE_A(cur ^ 1, (t + 1) << 6);
      if (p == 1 && t + 2 < nt) STAGE_B_LO(cur, (t + 2) << 6);
      if (p == 2 && t + 2 < nt) STAGE_B_HI(cur, (t + 2) << 6);

      __builtin_amdgcn_s_barrier();
      asm volatile("s_waitcnt lgkmcnt(0)" ::: "memory");
      __builtin_amdgcn_sched_barrier(0);
      __builtin_amdgcn_s_setprio(1);
      #pragma unroll
      for (int mm = 0; mm < 2; ++mm)
        #pragma unroll
        for (int n = 0; n < 4; ++n)
          #pragma unroll
          for (int kc = 0; kc < 2; ++kc)
            acc[2 * p + mm][n] = __builtin_amdgcn_mfma_f32_16x16x32_bf16(
                af[mm][kc], bf[n][kc], acc[2 * p + mm][n], 0, 0, 0);
      __builtin_amdgcn_s_setprio(0);
      if (p < 3) {
        __builtin_amdgcn_s_barrier();
      } else {
        if (t + 2 < nt) asm volatile("s_waitcnt vmcnt(4)" ::: "memory");
        else            asm volatile("s_waitcnt vmcnt(0)" ::: "memory");
        __builtin_amdgcn_s_barrier();
      }
    }
  }

  if (QKV == 1 && bn >= 4) {
    __syncthreads();
    short* T = smem;
    #pragma unroll
    for (int m = 0; m < 8; ++m)
      #pragma unroll
      for (int n = 0; n < 4; ++n) {
        int c = (wn * 4 + n) * 16 + l16;
        #pragma unroll
        for (int r = 0; r < 4; ++r) {
          int rowl = wm * 128 + m * 16 + lq * 4 + r;
          T[c * 256 + (rowl ^ ((c & 7) << 4))] = f2bf(acc[m][n][r]);
        }
      }
    __syncthreads();
    int b2 = bm >> 3;
    int nnb = (bm & 7) * 256;
    int tn = tid & 31, cw = tid >> 5;
    #pragma unroll
    for (int c8 = 0; c8 < 16; ++c8) {
      int c = c8 * 16 + cw;
      short8 v = *(const short8*)(T + c * 256 + ((tn * 8) ^ ((c & 7) << 4)));
      if (tn & 1) {
        short8 w;
        #pragma unroll
        for (int j = 0; j < 8; ++j) w[j] = v[j ^ 4];
        v = w;
      }
      int c2 = bn * 256 + c - 1024;
      int bh = b2 * 8 + (c2 >> 6);
      int d  = c2 & 63;
      *(short8*)(vt + ((size_t)(bh * 64 + d)) * 2048 + nnb + tn * 8) = v;
    }
    return;
  }

  float bv[4];
  if (QKV == 0) {
    #pragma unroll
    for (int n = 0; n < 4; ++n)
      bv[n] = bias[bn * 256 + (wn * 4 + n) * 16 + l16];
  }
  #pragma unroll
  for (int m = 0; m < 8; ++m) {
    #pragma unroll
    for (int r = 0; r < 4; ++r) {
      int row = bm * 256 + wm * 128 + m * 16 + lq * 4 + r;
      #pragma unroll
      for (int n = 0; n < 4; ++n) {
        int col = bn * 256 + (wn * 4 + n) * 16 + l16;
        float v = acc[m][n][r];
        if (QKV == 0) v = gelu_fast(v + bv[n]);
        C[(size_t)row * N + col] = f2bf(v);
      }
    }
  }
}

// ---------------- fused flash attention, split-KV x2, 8-wave blocks (LSA diag mask) ----------------
// measured-best: 512 threads / 8 waves / 256 q-rows per block; split-KV x2; grid 512.
// Fixed m=0 softmax => slice partials are PURE SUMS. Swapped-operand S^T = mfma(K,Q);
// in-register softmax; cvt_pk + 2-round shfl butterfly hands P^T to PV.
__global__ __launch_bounds__(512, 4) void attn_kernel(
    const short* __restrict__ qkv, const short* __restrict__ vt,
    const float* __restrict__ temp_ptr,
    short* __restrict__ Op0, short* __restrict__ Op1, float* __restrict__ Lbuf)
{
  __shared__ __align__(16) short smem[16384];  // Ks[2][4096] | Vs[2][4096]

  int tid = threadIdx.x;
  int lane = tid & 63, wid = tid >> 6;         // wid 0..7
  int l16 = lane & 15, lq = lane >> 4;
  int hi = lq >> 1, lq0 = lq & 1;

  int orig = blockIdx.y * 8 + blockIdx.x;      // nwg = 512
  int swz = (orig & 7) * 64 + (orig >> 3);
  int qb = swz & 7;
  int rr = swz >> 3;
  int bh = rr & 31, slice = rr >> 5;
  int b = bh >> 3, h = bh & 7;

  const short* qbase = qkv + (size_t)b * 2048 * 1536 + h * 64;
  const short* kbase = qbase + 512;
  const short* vbase = vt + (size_t)bh * 64 * 2048;
  int kslice = slice * 1024;

  float scale = __expf(temp_ptr[0]) * 1.44269504f;
  int q0 = qb * 256 + wid * 32;

  short8 qfrag[2][2];
  #pragma unroll
  for (int qf = 0; qf < 2; ++qf) {
    int qrow = q0 + qf * 16 + l16;
    #pragma unroll
    for (int c = 0; c < 2; ++c) {
      short8 raw = *(const short8*)(qbase + (size_t)qrow * 1536 + c * 32 + lq * 8);
      short8 sc;
      #pragma unroll
      for (int j = 0; j < 8; ++j) sc[j] = f2bf(bf2f(raw[j]) * scale);
      qfrag[qf][c] = sc;
    }
  }

  f32x4 accO[2][4] = {};
  float l[2] = {0.f, 0.f};

  auto STAGE = [&](int bufi, int k0) {
    int sub = wid >> 1, cc = wid & 1;
    const short* srcK = kbase + (size_t)(k0 + sub * 16 + l16) * 1536 + cc * 32 + lq * 8;
    gload_lds16(srcK, smem + bufi * 4096 + wid * 512);
    const short* srcV = vbase + (size_t)(sub * 16 + l16) * 2048 + k0 + cc * 32 + lq * 8;
    gload_lds16(srcV, smem + 8192 + bufi * 4096 + wid * 512);
  };

  STAGE(0, kslice);
  asm volatile("s_waitcnt vmcnt(0)");
  __syncthreads();

  for (int t = 0; t < 16; ++t) {
    int cur = t & 1;
    int k0 = kslice + t * 64;
    if (t + 1 < 16) STAGE(cur ^ 1, k0 + 64);

    const short* kls = smem + cur * 4096;
    const short* vls = smem + 8192 + cur * 4096;

    f32x4 accS[2][4] = {};
    #pragma unroll
    for (int s = 0; s < 4; ++s) {
      short8 kf0 = *(const short8*)(kls + (s * 2 + 0) * 512 + lane * 8);
      short8 kf1 = *(const short8*)(kls + (s * 2 + 1) * 512 + lane * 8);
      #pragma unroll
      for (int qf = 0; qf < 2; ++qf) {
        accS[qf][s] = __builtin_amdgcn_mfma_f32_16x16x32_bf16(kf0, qfrag[qf][0], accS[qf][s], 0, 0, 0);
        accS[qf][s] = __builtin_amdgcn_mfma_f32_16x16x32_bf16(kf1, qfrag[qf][1], accS[qf][s], 0, 0, 0);
      }
    }

    if ((q0 & ~63) == k0) {
      #pragma unroll
      for (int qf = 0; qf < 2; ++qf) {
        int qg = q0 + qf * 16 + l16;
        #pragma unroll
        for (int s = 0; s < 4; ++s)
          #pragma unroll
          for (int r = 0; r < 4; ++r)
            if (k0 + s * 16 + lq * 4 + r == qg) accS[qf][s][r] = -30000.f;
      }
    }

    short8 pa[2][2];
    #pragma unroll
    for (int qf = 0; qf < 2; ++qf) {
      float sum = 0.f;
      unsigned W[4][2];
      #pragma unroll
      for (int s = 0; s < 4; ++s) {
        float p0 = exp2_hw(accS[qf][s][0]);
        float p1 = exp2_hw(accS[qf][s][1]);
        float p2 = exp2_hw(accS[qf][s][2]);
        float p3 = exp2_hw(accS[qf][s][3]);
        sum += (p0 + p1) + (p2 + p3);
        W[s][0] = cvtpk(p0, p1);
        W[s][1] = cvtpk(p2, p3);
      }
      sum += __shfl_xor(sum, 16);
      sum += __shfl_xor(sum, 32);
      l[qf] += sum;

      unsigned K0[2], S0[2], K2[2], S2[2], R0[2], R2[2];
      #pragma unroll
      for (int w = 0; w < 2; ++w) {
        K0[w] = hi ? W[1][w] : W[0][w];
        S0[w] = hi ? W[0][w] : W[1][w];
        K2[w] = hi ? W[3][w] : W[2][w];
        S2[w] = hi ? W[2][w] : W[3][w];
      }
      #pragma unroll
      for (int w = 0; w < 2; ++w) {
        R0[w] = (unsigned)__shfl_xor((int)S0[w], 32);
        R2[w] = (unsigned)__shfl_xor((int)S2[w], 32);
      }
      bool sw = (hi != lq0);
      unsigned FA[2], FB[2], sA[2], sB[2], GA[2], GB[2];
      #pragma unroll
      for (int w = 0; w < 2; ++w) {
        sA[w] = sw ? K0[w] : R0[w];  FA[w] = sw ? R0[w] : K0[w];
        sB[w] = sw ? K2[w] : R2[w];  FB[w] = sw ? R2[w] : K2[w];
      }
      #pragma unroll
      for (int w = 0; w < 2; ++w) {
        GA[w] = (unsigned)__shfl_xor((int)sA[w], 16);
        GB[w] = (unsigned)__shfl_xor((int)sB[w], 16);
      }
      union { unsigned u[4]; short8 s8; } p0u, p1u;
      p0u.u[0] = FA[0]; p0u.u[1] = FA[1]; p0u.u[2] = GA[0]; p0u.u[3] = GA[1];
      p1u.u[0] = FB[0]; p1u.u[1] = FB[1]; p1u.u[2] = GB[0]; p1u.u[3] = GB[1];
      pa[qf][0] = p0u.s8;
      pa[qf][1] = p1u.s8;
    }

    short8 vfr[4][2];
    #pragma unroll
    for (int d = 0; d < 4; ++d) {
      vfr[d][0] = *(const short8*)(vls + (d * 2 + 0) * 512 + lane * 8);
      vfr[d][1] = *(const short8*)(vls + (d * 2 + 1) * 512 + lane * 8);
    }
    #pragma unroll
    for (int qf = 0; qf < 2; ++qf)
      #pragma unroll
      for (int d = 0; d < 4; ++d) {
        accO[qf][d] = __builtin_amdgcn_mfma_f32_16x16x32_bf16(vfr[d][0], pa[qf][0], accO[qf][d], 0, 0, 0);
        accO[qf][d] = __builtin_amdgcn_mfma_f32_16x16x32_bf16(vfr[d][1], pa[qf][1], accO[qf][d], 0, 0, 0);
      }

    __syncthreads();
  }

  short* op = slice ? Op1 : Op0;
  #pragma unroll
  for (int qf = 0; qf < 2; ++qf) {
    int qg = q0 + qf * 16 + l16;
    if (lq == 0) Lbuf[(size_t)(slice * 32 + bh) * 2048 + qg] = l[qf];
    size_t rowoff = (size_t)(b * 2048 + qg) * 512 + h * 64;
    #pragma unroll
    for (int d = 0; d < 4; ++d) {
      unsigned w0 = cvtpk(accO[qf][d][0], accO[qf][d][1]);
      unsigned w1 = cvtpk(accO[qf][d][2], accO[qf][d][3]);
      uint2 pk; pk.x = w0; pk.y = w1;
      *(uint2*)(op + rowoff + d * 16 + lq * 4) = pk;
    }
  }
}

// ---------------- split-KV combine: out = (O0+O1)/(l0+l1) ----------------
__global__ __launch_bounds__(256) void attn_combine_kernel(
    const short* __restrict__ Op0, const short* __restrict__ Op1,
    const float* __restrict__ Lbuf, short* __restrict__ out)
{
  int idx = blockIdx.x * 256 + threadIdx.x;
  size_t e = (size_t)idx * 8;
  int row = (int)(e >> 9);
  int col = (int)(e & 511);
  int b = row >> 11, q = row & 2047;
  int bh = b * 8 + (col >> 6);
  float l0 = Lbuf[(size_t)bh * 2048 + q];
  float l1 = Lbuf[(size_t)(32 + bh) * 2048 + q];
  float inv = rcp_hw(l0 + l1);
  short8 a = *(const short8*)(Op0 + e);
  short8 c = *(const short8*)(Op1 + e);
  float o[8];
  #pragma unroll
  for (int j = 0; j < 8; ++j) o[j] = (bf2f(a[j]) + bf2f(c[j])) * inv;
  uint4 pk;
  pk.x = cvtpk(o[0], o[1]); pk.y = cvtpk(o[2], o[3]);
  pk.z = cvtpk(o[4], o[5]); pk.w = cvtpk(o[6], o[7]);
  *(uint4*)(out + e) = pk;
}

// ---------------- launcher ----------------
extern "C" void kernel_launch(void* const* d_in, const int* in_sizes, int n_in,
                              void* d_out, int out_size, void* d_ws, size_t ws_size,
                              hipStream_t stream)
{
  const float* x    = (const float*)d_in[0];
  const float* ln1g = (const float*)d_in[1];
  const float* ln1b = (const float*)d_in[2];
  const float* Wqkv = (const float*)d_in[3];
  const float* temp = (const float*)d_in[4];
  const float* Wo   = (const float*)d_in[5];
  const float* bo   = (const float*)d_in[6];
  const float* ln2g = (const float*)d_in[7];
  const float* ln2b = (const float*)d_in[8];
  const float* W1   = (const float*)d_in[9];
  const float* b1   = (const float*)d_in[10];
  const float* W2   = (const float*)d_in[11];
  const float* b2   = (const float*)d_in[12];
  float* out = (float*)d_out;

  char* ws = (char*)d_ws;
  short* wqkv_t = (short*)(ws);                    // [1536][512] bf16; dead after qkv GEMM
  float* lpart  = (float*)(ws);                    //   reuse: l partials [2][32][2048] f32
  short* wo_t   = (short*)(ws + 1572864);          // [512][512]
  short* w1_t   = (short*)(ws + 2097152);          // [2048][512]
  short* w2_t   = (short*)(ws + 4194304);          // [512][2048]
  short* h      = (short*)(ws + 6291456);          // [8192][512] bf16 (LN out; O-partial slice1)
  short* qkv    = (short*)(ws + 14680064);         // [8192][1536] bf16
  short* attn   = (short*)(ws + 39845888);         // [8192][512] bf16 (slice0 -> combined)
  short* ybf    = (short*)(ws + 48234496);         // [8192][512] bf16 (after attn; overlays vt)
  short* vt     = (short*)(ws + 48234496);         // [32][64][2048] bf16 (dead once ybf written)
  short* t      = (short*)(ws + 14680064);         // [8192][2048] bf16 (reuses qkv)
  // ws high-water: 65,011,712 bytes (unchanged)

  const int M = 8192;

  prep_kernel<<<3072 + 2048, 256, 0, stream>>>(
      Wqkv, wqkv_t, Wo, wo_t, W1, w1_t, W2, w2_t,
      x, ln1g, ln1b, h, out + (size_t)M * 512);

  gemm8p_kernel<1><<<dim3(1536 / 256, M / 256), 512, 0, stream>>>(
      h, wqkv_t, qkv, nullptr, vt, M, 1536, 512);

  attn_kernel<<<dim3(8, 64), 512, 0, stream>>>(qkv, vt, temp, attn, h, lpart);
  attn_combine_kernel<<<M * 512 / 8 / 256, 256, 0, stream>>>(attn, h, lpart, attn);

  gemm_bt_kernel<4, 64, short><<<dim3(512 / 128, M / 64), 256, 0, stream>>>(
      attn, wo_t, ybf, bo, x, nullptr, M, 512, 512);

  ln_bf_kernel<<<M / 4, 256, 0, stream>>>(ybf, ln2g, ln2b, h);

  gemm8p_kernel<0><<<dim3(2048 / 256, M / 256), 512, 0, stream>>>(
      h, w1_t, t, b1, nullptr, M, 2048, 512);

  gemm_bt_kernel<5, 64, float><<<dim3(512 / 128, M / 64), 256, 0, stream>>>(
      t, w2_t, out, b2, nullptr, ybf, M, 512, 2048);
}